// Round 7
// baseline (568.329 us; speedup 1.0000x reference)
//
#include <hip/hip_runtime.h>
#include <hip/hip_bf16.h>
#include <hip/hip_fp16.h>

// ---------------------------------------------------------------------------
// GAT (4 layers + fc) on MI355X. ELL-gather formulation (no float atomics).
// flags[0]: float tensors bf16(1)/fp32(0); flags[1]: edges int64(1)/int32(0)
// fp32 compute; h AND inter-layer x stored fp16; fp32 output.
// R23: fuse row-local GEMMs into gather epilogues. After the cross-lane
//      reduce, y[d] is in wave registers and x_next = y@W+b is row-local:
//        gather1(F=32)+gemm1(32->64): 32-shfl broadcast, lane j -> x2[j],
//          layer-2 alpha fused in-register (was gemm1 relu_alpha path).
//        gather2(F=64)+gemm2(64->128): 64 shfl steps, 2 outs/lane.
//        gather3(F=128)+fc(128->16): lanes 0-15 hold x4; 8x16 partials +
//          4-round reduce; lane 0 writes 16 fp32 to d_out (x4 never stored).
//      18 -> 15 dispatches; kills gemm1/gemm2/fc + ~45MB round-trip traffic.
//      y stays fp32 (better precision than old fp16 round-trip).
// R22: gather inner loop = R19 exactly (NB=4 unpredicated, 36 VGPR, 60% occ);
//      R20 predication and R21 NB=8 both regressed. gather3's 50us is the
//      random-access roofline (155MB = 8 XCDs x 12.8MB compulsory).
// R19: atomic-free global max (blkmax + 1-block finalize).
// R18: x-side aggregation for FIN<FOUT layers (1,2).
// R17: atomic-free ELL build (chunk-histogram counting sort).
// ---------------------------------------------------------------------------

__device__ __forceinline__ float bf2f(unsigned short w) {
    return __uint_as_float(((unsigned int)w) << 16);
}
__device__ __forceinline__ unsigned enc_f(float f) {
    unsigned u = __float_as_uint(f);
    return (u & 0x80000000u) ? ~u : (u | 0x80000000u);
}
__device__ __forceinline__ float dec_f(unsigned u) {
    unsigned v = (u & 0x80000000u) ? (u & 0x7FFFFFFFu) : ~u;
    return __uint_as_float(v);
}

#define ELL_K 96    // slots per dst: 192 B = exactly 3 cache lines
#define NCHUNK 256  // chunk-histogram chunks (= K_B grid; K_C assumes 8x32)

// --------------------------- dtype detection -------------------------------
__global__ void detect_kernel(const unsigned short* __restrict__ xw,
                              const int* __restrict__ ew,
                              int* __restrict__ flags,
                              unsigned* __restrict__ maxbuf)
{
    __shared__ int cnt_sane[256];
    __shared__ int cnt_nz[256];
    const int t = threadIdx.x;
    unsigned short w = xw[2 * t];
    int e = (w >> 7) & 0xff;
    cnt_sane[t] = (e >= 110 && e <= 133) ? 1 : 0;
    cnt_nz[t] = (ew[2 * t + 1] != 0) ? 1 : 0;
    if (t < 8) maxbuf[t] = 0u;
    __syncthreads();
    if (t == 0) {
        int s = 0, nz = 0;
        for (int i = 0; i < 256; ++i) { s += cnt_sane[i]; nz += cnt_nz[i]; }
        flags[0] = (s >= 128) ? 1 : 0;
        flags[1] = (nz == 0) ? 1 : 0;
    }
}

// ------------------- param conversion + fused wvec -------------------------
struct ParamPtrs {
    const void* src[18];
    int n[18];
    int off[18];
};

__global__ void convert_params_kernel(ParamPtrs pp, const int* __restrict__ flags,
                                      float* __restrict__ out, float* __restrict__ wsd)
{
    const int b = blockIdx.x;
    const int bf = flags[0];
    if (b < 18) {
        const int n = pp.n[b];
        const float* fp = (const float*)pp.src[b];
        const unsigned short* hp = (const unsigned short*)pp.src[b];
        float* o = out + pp.off[b];
        for (int i = threadIdx.x; i < n; i += blockDim.x)
            o[i] = bf ? bf2f(hp[i]) : fp[i];
        return;
    }
    const int l = b - 18;                     // 0: layer1 (32x64), 1: layer2 (64x128)
    const int wi = l ? 8 : 4;                 // param index of W
    const unsigned short* Wh  = (const unsigned short*)pp.src[wi];
    const float*          Wf  = (const float*)pp.src[wi];
    const unsigned short* Ash = (const unsigned short*)pp.src[wi + 1];
    const float*          Asf = (const float*)pp.src[wi + 1];
    const unsigned short* Adh = (const unsigned short*)pp.src[wi + 2];
    const float*          Adf = (const float*)pp.src[wi + 2];
    const int FIN  = l ? 64 : 32;
    const int FOUT = l ? 128 : 64;
    float* ws = wsd + l * 256;
    float* wd = ws + 128;
    const int k = threadIdx.x;
    if (k < FIN) {
        float s = 0.f, d = 0.f;
        for (int j = 0; j < FOUT; ++j) {
            const float w = bf ? bf2f(Wh[k * FOUT + j]) : Wf[k * FOUT + j];
            const float a = bf ? bf2f(Ash[j]) : Asf[j];
            const float c = bf ? bf2f(Adh[j]) : Adf[j];
            s += w * a;
            d += w * c;
        }
        ws[k] = s;
        wd[k] = d;
    }
}

// ---------------- global-max finalize (atomic-free) ------------------------
__global__ __launch_bounds__(256) void max_finalize_kernel(
    const float2* __restrict__ bm, int nb, unsigned* __restrict__ maxSD)
{
    __shared__ float sm[4][2];
    const int tx = threadIdx.x;
    float ms = -INFINITY, md = -INFINITY;
    for (int i = tx; i < nb; i += 256) {
        const float2 v = bm[i];
        ms = fmaxf(ms, v.x);
        md = fmaxf(md, v.y);
    }
    #pragma unroll
    for (int off = 32; off > 0; off >>= 1) {
        ms = fmaxf(ms, __shfl_down(ms, off, 64));
        md = fmaxf(md, __shfl_down(md, off, 64));
    }
    if ((tx & 63) == 0) { sm[tx >> 6][0] = ms; sm[tx >> 6][1] = md; }
    __syncthreads();
    if (tx == 0) {
        #pragma unroll
        for (int w = 1; w < 4; ++w) {
            ms = fmaxf(ms, sm[w][0]);
            md = fmaxf(md, sm[w][1]);
        }
        maxSD[0] = enc_f(ms);
        maxSD[1] = enc_f(md);
    }
}

// ---------------- K_B: per-chunk histogram + sd pack (LDS atomics only) ----
__global__ __launch_bounds__(1024) void hist_pack_kernel(
    const int* __restrict__ e, const int* __restrict__ flags,
    unsigned* __restrict__ sd, unsigned* __restrict__ hist,
    long long E, long long Et, int chunk, int NQ)
{
    extern __shared__ unsigned hcnt[];          // NQ words = ceil(N/4)*4 B
    const int c = blockIdx.x;
    for (int i = threadIdx.x; i < NQ; i += 1024) hcnt[i] = 0u;
    __syncthreads();
    const int f64 = flags[1];
    const long long c0 = (long long)c * chunk;
    long long c1 = c0 + chunk; if (c1 > Et) c1 = Et;
    for (long long t = c0 + threadIdx.x; t < c1; t += 1024) {
        int s, d;
        if (t >= E) { s = (int)(t - E); d = s; }
        else if (f64) { s = e[2 * t]; d = e[2 * E + 2 * t]; }
        else          { s = e[t];     d = e[E + t]; }
        sd[t] = (unsigned)s | ((unsigned)d << 16);
        atomicAdd(&hcnt[d >> 2], 1u << ((d & 3) << 3));
    }
    __syncthreads();
    unsigned* hrow = hist + (size_t)c * NQ;
    for (int i = threadIdx.x; i < NQ; i += 1024) hrow[i] = hcnt[i];
}

// ---------------- K_C: per-dst exclusive prefix over chunks ----------------
__global__ __launch_bounds__(256) void chunk_scan_kernel(
    const unsigned* __restrict__ hist, unsigned* __restrict__ base32,
    int* __restrict__ deg, int NQ, int N)
{
    __shared__ unsigned short sums[32][8][4];   // [dql][oct][byte]
    const int dql = threadIdx.x & 31;
    const int oct = threadIdx.x >> 5;           // 0..7, 32 chunks each
    const int dq  = blockIdx.x * 32 + dql;
    const int cbeg = oct * 32;

    unsigned s0 = 0, s1 = 0, s2 = 0, s3 = 0;
    if (dq < NQ) {
        const unsigned* hp = hist + (size_t)cbeg * NQ + dq;
        #pragma unroll 8
        for (int c = 0; c < 32; ++c) {
            const unsigned v = hp[(size_t)c * NQ];
            s0 += v & 0xffu;          s1 += (v >> 8) & 0xffu;
            s2 += (v >> 16) & 0xffu;  s3 += v >> 24;
        }
    }
    sums[dql][oct][0] = (unsigned short)s0;
    sums[dql][oct][1] = (unsigned short)s1;
    sums[dql][oct][2] = (unsigned short)s2;
    sums[dql][oct][3] = (unsigned short)s3;
    __syncthreads();

    unsigned r0 = 0, r1 = 0, r2 = 0, r3 = 0;    // exclusive octant prefix
    #pragma unroll
    for (int p = 0; p < 8; ++p) {
        if (p < oct) {
            r0 += sums[dql][p][0]; r1 += sums[dql][p][1];
            r2 += sums[dql][p][2]; r3 += sums[dql][p][3];
        }
    }
    if (dq >= NQ) return;

    if (oct == 7) {                              // totals -> deg
        const int d0 = dq * 4;
        const int t0 = (int)(r0 + s0), t1 = (int)(r1 + s1);
        const int t2 = (int)(r2 + s2), t3 = (int)(r3 + s3);
        if (d0 + 3 < N) {
            *(int4*)(deg + d0) = make_int4(t0, t1, t2, t3);
        } else {
            if (d0     < N) deg[d0]     = t0;
            if (d0 + 1 < N) deg[d0 + 1] = t1;
            if (d0 + 2 < N) deg[d0 + 2] = t2;
            if (d0 + 3 < N) deg[d0 + 3] = t3;
        }
    }

    // exclusive running bases for this octant's 32 chunks
    unsigned run0 = r0, run1 = r1, run2 = r2, run3 = r3;
    const unsigned* hp = hist + (size_t)cbeg * NQ + dq;
    unsigned* bp = base32 + (size_t)cbeg * NQ + dq;
    for (int c = 0; c < 32; ++c) {
        const unsigned v = hp[(size_t)c * NQ];
        const unsigned o = (run0 < 255u ? run0 : 255u)
                         | ((run1 < 255u ? run1 : 255u) << 8)
                         | ((run2 < 255u ? run2 : 255u) << 16)
                         | ((run3 < 255u ? run3 : 255u) << 24);
        bp[(size_t)c * NQ] = o;
        run0 += v & 0xffu;          run1 += (v >> 8) & 0xffu;
        run2 += (v >> 16) & 0xffu;  run3 += v >> 24;
    }
}

// ---------------- K_D: bucketed ELL fill (atomic-free globally) ------------
__global__ __launch_bounds__(256) void ell_fill_kernel(
    const unsigned* __restrict__ sd, const unsigned* __restrict__ base32,
    unsigned short* __restrict__ ell16, long long Et, int chunk, int NQ, int shift)
{
    extern __shared__ unsigned cnt[];            // (1<<shift)/4 words
    const int bucket = blockIdx.x & 7;
    const int c = blockIdx.x >> 3;
    const int words = (1 << shift) >> 2;
    for (int i = threadIdx.x; i < words; i += 256) cnt[i] = 0u;
    __syncthreads();
    const long long c0 = (long long)c * chunk;
    long long c1 = c0 + chunk; if (c1 > Et) c1 = Et;
    const unsigned* brow = base32 + (size_t)c * NQ;
    const int dlo = bucket << shift;
    for (long long i = c0 + threadIdx.x; i < c1; i += 256) {
        const unsigned v = sd[i];
        const int d = (int)(v >> 16);
        if ((d >> shift) != bucket) continue;
        const int dl = d - dlo;
        const unsigned sh = (unsigned)((dl & 3) << 3);
        const unsigned old = atomicAdd(&cnt[dl >> 2], 1u << sh);
        const unsigned lr = (old >> sh) & 0xffu;
        const unsigned b = (brow[d >> 2] >> ((d & 3) << 3)) & 0xffu;
        const unsigned slot = b + lr;
        if (slot < ELL_K)
            ell16[(long long)d * ELL_K + slot] = (unsigned short)(v & 0xffffu);
    }
}

// ------------------------------- GEMM --------------------------------------
// Register-blocked: 256 threads, TM=64 rows/block; thread (cg,rt) = RR rows x
// 4 cols. W [FIN][FOUT] lane-coalesced. Fused alpha dots (fp32 acc) + per-
// block max -> blkmax (no atomics).
struct Half4 { __half2 a, b; };

__device__ __forceinline__ void store4(float* h, long long idx, const float* a) {
    *(float4*)(h + idx) = make_float4(a[0], a[1], a[2], a[3]);
}
__device__ __forceinline__ void store4(__half* h, long long idx, const float* a) {
    Half4 v;
    v.a = __floats2half2_rn(a[0], a[1]);
    v.b = __floats2half2_rn(a[2], a[3]);
    *(Half4*)(h + idx) = v;
}

template <int FIN, int FOUT, typename OT>
__global__ __launch_bounds__(256) void gemm_alpha_kernel(
    const void* __restrict__ xv, const int* __restrict__ flags, int x_ext,
    const float* __restrict__ W, const float* __restrict__ a_src,
    const float* __restrict__ a_dst, const float* __restrict__ bias,
    OT* __restrict__ h,
    float* __restrict__ alpha_s, float* __restrict__ alpha_d,
    float2* __restrict__ blkmax, int has_alpha,
    int N, int relu_in, int has_bias, int relu_alpha)
{
    constexpr int CG = FOUT / 4;
    constexpr int RT = 256 / CG;
    constexpr int RR = 64 / RT;
    constexpr int TM = 64;
    constexpr int XP = FIN + 4;
    constexpr int Q  = FIN / 8;      // 8-float groups per row

    __shared__ float xs[TM * XP];
    __shared__ float red[2][TM][CG + 1];

    const int tx = threadIdx.x;
    const int cg = tx & (CG - 1);
    const int rt = tx / CG;
    const long long base = (long long)blockIdx.x * TM;

    const int xbf = x_ext ? flags[0] : 0;

    for (int idx = tx; idx < TM * Q; idx += 256) {
        const int r  = idx / Q;
        const int c8 = idx - r * Q;
        const long long grow = base + r;
        float v[8] = {0.f, 0.f, 0.f, 0.f, 0.f, 0.f, 0.f, 0.f};
        if (grow < N) {
            const long long gi = grow * FIN + 8 * c8;
            if (x_ext) {
                if (xbf) {
                    const unsigned short* xp = (const unsigned short*)xv + gi;
                    #pragma unroll
                    for (int u = 0; u < 8; ++u) v[u] = bf2f(xp[u]);
                } else {
                    const float4 f0 = *((const float4*)((const float*)xv + gi));
                    const float4 f1 = *((const float4*)((const float*)xv + gi + 4));
                    v[0] = f0.x; v[1] = f0.y; v[2] = f0.z; v[3] = f0.w;
                    v[4] = f1.x; v[5] = f1.y; v[6] = f1.z; v[7] = f1.w;
                }
            } else {
                const float4 raw = *((const float4*)((const __half*)xv + gi)); // 8 halfs
                const __half2* q = (const __half2*)&raw;
                const float2 a0 = __half22float2(q[0]);
                const float2 a1 = __half22float2(q[1]);
                const float2 a2 = __half22float2(q[2]);
                const float2 a3 = __half22float2(q[3]);
                v[0] = a0.x; v[1] = a0.y; v[2] = a1.x; v[3] = a1.y;
                v[4] = a2.x; v[5] = a2.y; v[6] = a3.x; v[7] = a3.y;
            }
            if (relu_in) {
                #pragma unroll
                for (int u = 0; u < 8; ++u) v[u] = fmaxf(v[u], 0.f);
            }
        }
        *(float4*)&xs[r * XP + 8 * c8]     = make_float4(v[0], v[1], v[2], v[3]);
        *(float4*)&xs[r * XP + 8 * c8 + 4] = make_float4(v[4], v[5], v[6], v[7]);
    }
    __syncthreads();

    float acc[RR][4];
    #pragma unroll
    for (int rr = 0; rr < RR; ++rr)
        { acc[rr][0] = acc[rr][1] = acc[rr][2] = acc[rr][3] = 0.f; }

    const int r0 = rt * RR;
    #pragma unroll 4
    for (int k = 0; k < FIN; ++k) {
        const float4 w4 = *(const float4*)(W + k * FOUT + 4 * cg);
        #pragma unroll
        for (int rr = 0; rr < RR; ++rr) {
            const float xval = xs[(r0 + rr) * XP + k];
            acc[rr][0] += xval * w4.x;
            acc[rr][1] += xval * w4.y;
            acc[rr][2] += xval * w4.z;
            acc[rr][3] += xval * w4.w;
        }
    }

    if (has_bias) {
        const float4 b4 = *(const float4*)(bias + 4 * cg);
        #pragma unroll
        for (int rr = 0; rr < RR; ++rr) {
            acc[rr][0] += b4.x; acc[rr][1] += b4.y;
            acc[rr][2] += b4.z; acc[rr][3] += b4.w;
        }
    }

    #pragma unroll
    for (int rr = 0; rr < RR; ++rr) {
        const long long grow = base + r0 + rr;
        if (grow < N)
            store4(h, grow * FOUT + 4 * cg, acc[rr]);
    }

    if (has_alpha) {
        const float4 as4 = *(const float4*)(a_src + 4 * cg);
        const float4 ad4 = *(const float4*)(a_dst + 4 * cg);
        #pragma unroll
        for (int rr = 0; rr < RR; ++rr) {
            float b0 = acc[rr][0], b1 = acc[rr][1], b2 = acc[rr][2], b3 = acc[rr][3];
            if (relu_alpha) {
                b0 = fmaxf(b0, 0.f); b1 = fmaxf(b1, 0.f);
                b2 = fmaxf(b2, 0.f); b3 = fmaxf(b3, 0.f);
            }
            red[0][r0 + rr][cg] = b0 * as4.x + b1 * as4.y + b2 * as4.z + b3 * as4.w;
            red[1][r0 + rr][cg] = b0 * ad4.x + b1 * ad4.y + b2 * ad4.z + b3 * ad4.w;
        }
        __syncthreads();
        if (tx < TM) {            // TM == 64: exactly wave 0
            float ss = 0.f, sd = 0.f;
            #pragma unroll
            for (int j = 0; j < CG; ++j) {
                ss += red[0][tx][j];
                sd += red[1][tx][j];
            }
            const long long grow = base + tx;
            const bool valid = grow < N;
            if (valid) { alpha_s[grow] = ss; alpha_d[grow] = sd; }
            float ms = valid ? ss : -INFINITY;
            float md = valid ? sd : -INFINITY;
            #pragma unroll
            for (int off = 32; off > 0; off >>= 1) {
                ms = fmaxf(ms, __shfl_down(ms, off, 64));
                md = fmaxf(md, __shfl_down(md, off, 64));
            }
            if (tx == 0)
                blkmax[blockIdx.x] = make_float2(ms, md);
        }
    }
}

// --------------------------- gather (per-dst wave) -------------------------
// Single pass: p = exp(leaky(as[s]+ad[d]) - M), M = global max shift.
// ELL: dst d's edges at ell16[d*96 .. d*96+cnt). h fp16.
// XRELU: relu gathered rows (x-side aggregation). ADDB: add bias to out row.
// AFUSE: fused next-layer alpha from out row (gather0).
// GF=0: plain fp16 out. GF=64: fused 32->64 GEMM (+next alpha via wsA/wdA).
// GF=128: fused 64->128 GEMM. GF=1: fused fc 128->16, fp32 outF (no x write).
// Inner loop: R19 structure EXACTLY (4-wide unpredicated burst).
template <int F, int XRELU, int ADDB, int AFUSE, int GF>
__global__ __launch_bounds__(256) void gat_gather_kernel(
    const int* __restrict__ deg, const unsigned short* __restrict__ ell16,
    const float* __restrict__ as, const float* __restrict__ ad,
    const unsigned* __restrict__ maxSD,
    const __half* __restrict__ h, const float* __restrict__ bias,
    __half* __restrict__ out, int N,
    const float* __restrict__ wsA, const float* __restrict__ wdA,
    float* __restrict__ asO, float* __restrict__ adO,
    float2* __restrict__ bmax,
    const float* __restrict__ Wn, const float* __restrict__ bn,
    float* __restrict__ outF)
{
    constexpr int LPE = F / 8;       // lanes per edge (4,8,16)
    constexpr int EPJ = 64 / LPE;    // edges per u-step (16,8,4)
    constexpr bool BMAX = (AFUSE != 0) || (GF == 64);

    const int wslot = threadIdx.x >> 6;
    const int lane = threadIdx.x & 63;
    const int d = blockIdx.x * 4 + wslot;
    const bool dvalid = d < N;
    if (!BMAX && !dvalid) return;

    float ssA = -INFINITY, sdA = -INFINITY;   // per-wave alpha partial (lane 0)

    float inv = 0.f;
    float a0 = 0.f, a1 = 0.f, a2 = 0.f, a3 = 0.f;
    float a4 = 0.f, a5 = 0.f, a6 = 0.f, a7 = 0.f;

    if (dvalid) {
        const float M = dec_f(maxSD[0]) + dec_f(maxSD[1]);
        const int cnt_all = min(deg[d], ELL_K);
        const long long e0 = (long long)d * ELL_K;
        const float add = ad[d];

        const int sub = lane / LPE;          // edge sub-slot
        const int fl  = (lane % LPE) * 8;    // feature offset (8 feats/lane)

        float den = 0.f;
        for (int base = 0; base < cnt_all; base += 64) {
            const int e = base + lane;
            float p = 0.f;
            int s = 0;
            if (e < cnt_all) {
                s = (int)ell16[e0 + e];
                float v = as[s] + add;
                v = (v > 0.f) ? v : 0.2f * v;
                p = expf(v - M);
            }
            den += p;
            const int cnt = min(64, cnt_all - base);
            // 4-wide burst: 4 independent float4 (=8 fp16) loads, then accumulate
            for (int j = 0; j < cnt; j += 4 * EPJ) {
                float pj[4];
                float4 hv[4];
                #pragma unroll
                for (int u = 0; u < 4; ++u) {
                    const int jj = j + u * EPJ + sub;       // < 64 always
                    pj[u] = __shfl(p, jj, 64);              // 0 for OOB slots
                    const int sj = __shfl(s, jj, 64);
                    hv[u] = *(const float4*)(h + (long long)sj * F + fl);
                }
                #pragma unroll
                for (int u = 0; u < 4; ++u) {
                    const __half2* q = (const __half2*)&hv[u];
                    float2 f0 = __half22float2(q[0]);
                    float2 f1 = __half22float2(q[1]);
                    float2 f2 = __half22float2(q[2]);
                    float2 f3 = __half22float2(q[3]);
                    if (XRELU) {
                        f0.x = fmaxf(f0.x, 0.f); f0.y = fmaxf(f0.y, 0.f);
                        f1.x = fmaxf(f1.x, 0.f); f1.y = fmaxf(f1.y, 0.f);
                        f2.x = fmaxf(f2.x, 0.f); f2.y = fmaxf(f2.y, 0.f);
                        f3.x = fmaxf(f3.x, 0.f); f3.y = fmaxf(f3.y, 0.f);
                    }
                    a0 += pj[u] * f0.x;  a1 += pj[u] * f0.y;
                    a2 += pj[u] * f1.x;  a3 += pj[u] * f1.y;
                    a4 += pj[u] * f2.x;  a5 += pj[u] * f2.y;
                    a6 += pj[u] * f3.x;  a7 += pj[u] * f3.y;
                }
            }
        }
        #pragma unroll
        for (int off = 32; off > 0; off >>= 1)
            den += __shfl_down(den, off, 64);
        den = __shfl(den, 0, 64);
        inv = 1.f / den;

        // combine edge sub-slots (lanes LPE apart hold same feature)
        #pragma unroll
        for (int off = 32; off >= LPE; off >>= 1) {
            a0 += __shfl_down(a0, off, 64);
            a1 += __shfl_down(a1, off, 64);
            a2 += __shfl_down(a2, off, 64);
            a3 += __shfl_down(a3, off, 64);
            a4 += __shfl_down(a4, off, 64);
            a5 += __shfl_down(a5, off, 64);
            a6 += __shfl_down(a6, off, 64);
            a7 += __shfl_down(a7, off, 64);
        }

        if (GF == 0) {
            if (lane < LPE) {
                const int fl2 = fl;
                float v0, v1, v2, v3, v4, v5, v6, v7;
                if (ADDB) {
                    const float4 bA = *(const float4*)(bias + fl2);
                    const float4 bB = *(const float4*)(bias + fl2 + 4);
                    v0 = bA.x + a0 * inv;  v1 = bA.y + a1 * inv;
                    v2 = bA.z + a2 * inv;  v3 = bA.w + a3 * inv;
                    v4 = bB.x + a4 * inv;  v5 = bB.y + a5 * inv;
                    v6 = bB.z + a6 * inv;  v7 = bB.w + a7 * inv;
                } else {
                    v0 = a0 * inv;  v1 = a1 * inv;  v2 = a2 * inv;  v3 = a3 * inv;
                    v4 = a4 * inv;  v5 = a5 * inv;  v6 = a6 * inv;  v7 = a7 * inv;
                }
                float4 pack;
                __half2* q = (__half2*)&pack;
                q[0] = __floats2half2_rn(v0, v1);
                q[1] = __floats2half2_rn(v2, v3);
                q[2] = __floats2half2_rn(v4, v5);
                q[3] = __floats2half2_rn(v6, v7);
                *(float4*)(out + (long long)d * F + fl2) = pack;   // 8 halfs

                if (AFUSE) {
                    const float4 wA = *(const float4*)(wsA + fl2);
                    const float4 wB = *(const float4*)(wsA + fl2 + 4);
                    const float4 dA = *(const float4*)(wdA + fl2);
                    const float4 dB = *(const float4*)(wdA + fl2 + 4);
                    const float r0 = fmaxf(v0, 0.f), r1 = fmaxf(v1, 0.f);
                    const float r2 = fmaxf(v2, 0.f), r3 = fmaxf(v3, 0.f);
                    const float r4 = fmaxf(v4, 0.f), r5 = fmaxf(v5, 0.f);
                    const float r6 = fmaxf(v6, 0.f), r7 = fmaxf(v7, 0.f);
                    float ss = r0 * wA.x + r1 * wA.y + r2 * wA.z + r3 * wA.w
                             + r4 * wB.x + r5 * wB.y + r6 * wB.z + r7 * wB.w;
                    float sdv = r0 * dA.x + r1 * dA.y + r2 * dA.z + r3 * dA.w
                              + r4 * dB.x + r5 * dB.y + r6 * dB.z + r7 * dB.w;
                    #pragma unroll
                    for (int off = LPE / 2; off > 0; off >>= 1) {
                        ss  += __shfl_down(ss, off, 64);
                        sdv += __shfl_down(sdv, off, 64);
                    }
                    if (lane == 0) {
                        asO[d] = ss;
                        adO[d] = sdv;
                        ssA = ss;
                        sdA = sdv;
                    }
                }
            }
        } else if (GF == 64) {
            // fused 32->64 GEMM: x2[j] = bn[j] + sum_f y_f * Wn[f*64+j]
            float xo = bn[lane];
            #define GSTEP(L, R) { const float y = __shfl(a##R, L, 64) * inv; \
                                  xo += y * Wn[((L) * 8 + (R)) * 64 + lane]; }
            GSTEP(0,0) GSTEP(0,1) GSTEP(0,2) GSTEP(0,3)
            GSTEP(0,4) GSTEP(0,5) GSTEP(0,6) GSTEP(0,7)
            GSTEP(1,0) GSTEP(1,1) GSTEP(1,2) GSTEP(1,3)
            GSTEP(1,4) GSTEP(1,5) GSTEP(1,6) GSTEP(1,7)
            GSTEP(2,0) GSTEP(2,1) GSTEP(2,2) GSTEP(2,3)
            GSTEP(2,4) GSTEP(2,5) GSTEP(2,6) GSTEP(2,7)
            GSTEP(3,0) GSTEP(3,1) GSTEP(3,2) GSTEP(3,3)
            GSTEP(3,4) GSTEP(3,5) GSTEP(3,6) GSTEP(3,7)
            #undef GSTEP
            out[(long long)d * 64 + lane] = __float2half(xo);
            // next-layer alpha from relu(x2)
            const float r = fmaxf(xo, 0.f);
            float ss = r * wsA[lane];
            float sdv = r * wdA[lane];
            #pragma unroll
            for (int off = 32; off > 0; off >>= 1) {
                ss  += __shfl_down(ss, off, 64);
                sdv += __shfl_down(sdv, off, 64);
            }
            if (lane == 0) {
                asO[d] = ss;
                adO[d] = sdv;
                ssA = ss;
                sdA = sdv;
            }
        } else if (GF == 128) {
            // fused 64->128 GEMM: 2 outputs/lane (2*lane, 2*lane+1)
            float xo0 = bn[2 * lane], xo1 = bn[2 * lane + 1];
            #define GSTEP(L, R) { const float y = __shfl(a##R, L, 64) * inv; \
                                  const float2 wv = *(const float2*)(Wn + ((L) * 8 + (R)) * 128 + 2 * lane); \
                                  xo0 += y * wv.x; xo1 += y * wv.y; }
            GSTEP(0,0) GSTEP(0,1) GSTEP(0,2) GSTEP(0,3)
            GSTEP(0,4) GSTEP(0,5) GSTEP(0,6) GSTEP(0,7)
            GSTEP(1,0) GSTEP(1,1) GSTEP(1,2) GSTEP(1,3)
            GSTEP(1,4) GSTEP(1,5) GSTEP(1,6) GSTEP(1,7)
            GSTEP(2,0) GSTEP(2,1) GSTEP(2,2) GSTEP(2,3)
            GSTEP(2,4) GSTEP(2,5) GSTEP(2,6) GSTEP(2,7)
            GSTEP(3,0) GSTEP(3,1) GSTEP(3,2) GSTEP(3,3)
            GSTEP(3,4) GSTEP(3,5) GSTEP(3,6) GSTEP(3,7)
            GSTEP(4,0) GSTEP(4,1) GSTEP(4,2) GSTEP(4,3)
            GSTEP(4,4) GSTEP(4,5) GSTEP(4,6) GSTEP(4,7)
            GSTEP(5,0) GSTEP(5,1) GSTEP(5,2) GSTEP(5,3)
            GSTEP(5,4) GSTEP(5,5) GSTEP(5,6) GSTEP(5,7)
            GSTEP(6,0) GSTEP(6,1) GSTEP(6,2) GSTEP(6,3)
            GSTEP(6,4) GSTEP(6,5) GSTEP(6,6) GSTEP(6,7)
            GSTEP(7,0) GSTEP(7,1) GSTEP(7,2) GSTEP(7,3)
            GSTEP(7,4) GSTEP(7,5) GSTEP(7,6) GSTEP(7,7)
            #undef GSTEP
            *(__half2*)(out + (long long)d * 128 + 2 * lane) =
                __floats2half2_rn(xo0, xo1);
        } else {  // GF == 1: fused fc 128->16, fp32 out
            float pacc[8];
            float r[8];
            bool have = false;
            if (lane < LPE) {
                const int fl2 = fl;
                const float4 bA = *(const float4*)(bias + fl2);
                const float4 bB = *(const float4*)(bias + fl2 + 4);
                r[0] = fmaxf(bA.x + a0 * inv, 0.f);
                r[1] = fmaxf(bA.y + a1 * inv, 0.f);
                r[2] = fmaxf(bA.z + a2 * inv, 0.f);
                r[3] = fmaxf(bA.w + a3 * inv, 0.f);
                r[4] = fmaxf(bB.x + a4 * inv, 0.f);
                r[5] = fmaxf(bB.y + a5 * inv, 0.f);
                r[6] = fmaxf(bB.z + a6 * inv, 0.f);
                r[7] = fmaxf(bB.w + a7 * inv, 0.f);
                have = true;
            }
            #pragma unroll
            for (int hi = 0; hi < 2; ++hi) {
                #pragma unroll
                for (int j = 0; j < 8; ++j) pacc[j] = 0.f;
                if (have) {
                    #pragma unroll
                    for (int k = 0; k < 8; ++k) {
                        const float4 wA = *(const float4*)(Wn + (fl + k) * 16 + hi * 8);
                        const float4 wB = *(const float4*)(Wn + (fl + k) * 16 + hi * 8 + 4);
                        pacc[0] += r[k] * wA.x;  pacc[1] += r[k] * wA.y;
                        pacc[2] += r[k] * wA.z;  pacc[3] += r[k] * wA.w;
                        pacc[4] += r[k] * wB.x;  pacc[5] += r[k] * wB.y;
                        pacc[6] += r[k] * wB.z;  pacc[7] += r[k] * wB.w;
                    }
                }
                #pragma unroll
                for (int off = 8; off > 0; off >>= 1) {
                    #pragma unroll
                    for (int j = 0; j < 8; ++j)
                        pacc[j] += __shfl_down(pacc[j], off, 64);
                }
                if (lane == 0) {
                    float4 o0 = make_float4(pacc[0] + bn[hi * 8 + 0],
                                            pacc[1] + bn[hi * 8 + 1],
                                            pacc[2] + bn[hi * 8 + 2],
                                            pacc[3] + bn[hi * 8 + 3]);
                    float4 o1 = make_float4(pacc[4] + bn[hi * 8 + 4],
                                            pacc[5] + bn[hi * 8 + 5],
                                            pacc[6] + bn[hi * 8 + 6],
                                            pacc[7] + bn[hi * 8 + 7]);
                    *(float4*)(outF + (long long)d * 16 + hi * 8)     = o0;
                    *(float4*)(outF + (long long)d * 16 + hi * 8 + 4) = o1;
                }
            }
        }
    }

    if (BMAX) {
        __shared__ float smx[4][2];
        if (lane == 0) {
            smx[wslot][0] = dvalid ? ssA : -INFINITY;
            smx[wslot][1] = dvalid ? sdA : -INFINITY;
        }
        __syncthreads();
        if (threadIdx.x == 0) {
            float ms = smx[0][0], md = smx[0][1];
            #pragma unroll
            for (int w = 1; w < 4; ++w) {
                ms = fmaxf(ms, smx[w][0]);
                md = fmaxf(md, smx[w][1]);
            }
            bmax[blockIdx.x] = make_float2(ms, md);
        }
    }
}

// ------------------------------- launch ------------------------------------
extern "C" void kernel_launch(void* const* d_in, const int* in_sizes, int n_in,
                              void* d_out, int out_size, void* d_ws, size_t ws_size,
                              hipStream_t stream)
{
    const int INP = 128;
    const int N = in_sizes[0] / INP;                 // 50000 (< 65536: ushort ok)
    const long long E = in_sizes[1] / 2;             // 1600000
    const long long Et = E + N;

    const int Fin[4]  = {128, 32, 64, 128};
    const int Fout[4] = {32, 64, 128, 128};

    const int NQ = (N + 3) / 4;                      // hist/base words per chunk
    const size_t histBytes = (size_t)NQ * 4 * NCHUNK;
    const size_t xbufBytes = (size_t)N * 128 * sizeof(__half);
    const size_t bigBytes  = histBytes > xbufBytes ? histBytes : xbufBytes;

    // ---- workspace layout (~44 MB) ----
    char* p = (char*)d_ws;
    auto alloc = [&](size_t bytes) {
        char* r = p;
        p += (bytes + 255) & ~(size_t)255;
        return r;
    };
    __half*   bufH    = (__half*)  alloc(bigBytes);  // aliases hist (K_B..K_C)
    __half*   bufX    = (__half*)  alloc(bigBytes);  // aliases base (K_C..K_D)
    float*    as      = (float*)   alloc((size_t)N * sizeof(float));
    float*    ad      = (float*)   alloc((size_t)N * sizeof(float));
    float*    as2     = (float*)   alloc((size_t)N * sizeof(float));
    float*    ad2     = (float*)   alloc((size_t)N * sizeof(float));
    int*      deg     = (int*)     alloc((size_t)N * sizeof(int));
    unsigned short* ell16 = (unsigned short*)alloc((size_t)N * ELL_K * sizeof(unsigned short));
    unsigned* sd      = (unsigned*)alloc((size_t)Et * sizeof(unsigned));
    unsigned* maxbuf  = (unsigned*)alloc(64);
    int*      flags   = (int*)     alloc(64);
    float*    wsd     = (float*)   alloc(512 * sizeof(float));
    float2*   blkmax  = (float2*)  alloc(16384 * sizeof(float2));
    float*    params  = (float*)   alloc(64 * 1024 * sizeof(float));
    (void)ws_size;

    unsigned* hist   = (unsigned*)bufH;   // dead before gemm0 writes bufH
    unsigned* base32 = (unsigned*)bufX;   // dead before gather0 writes bufX

    // ---- dtype detection + maxbuf init ----
    detect_kernel<<<1, 256, 0, stream>>>((const unsigned short*)d_in[0],
                                         (const int*)d_in[1], flags, maxbuf);

    // ---- param conversion + wvec (blocks 18,19) ----
    ParamPtrs pp;
    int off = 0;
    {
        int k = 0;
        for (int i = 0; i < 4; ++i) {
            pp.n[k++] = Fin[i] * Fout[i];
            pp.n[k++] = Fout[i];
            pp.n[k++] = Fout[i];
            pp.n[k++] = Fout[i];
        }
        pp.n[16] = 128 * 16;
        pp.n[17] = 16;
        for (int i = 0; i < 18; ++i) {
            pp.src[i] = d_in[2 + i];
            pp.off[i] = off;
            off += pp.n[i];
        }
    }
    convert_params_kernel<<<20, 256, 0, stream>>>(pp, flags, params, wsd);

    const float* Wl[4], *asr[4], *adt[4], *bl[4];
    for (int i = 0; i < 4; ++i) {
        Wl[i]  = params + pp.off[4 * i + 0];
        asr[i] = params + pp.off[4 * i + 1];
        adt[i] = params + pp.off[4 * i + 2];
        bl[i]  = params + pp.off[4 * i + 3];
    }
    const float* fcW = params + pp.off[16];
    const float* fcb = params + pp.off[17];

    const int* e32 = (const int*)d_in[1];

    // ---- ELL build: chunk histogram -> scan -> bucketed fill (atomic-free) -
    {
        const int chunk = (int)((Et + NCHUNK - 1) / NCHUNK);
        int shift = 0;
        while ((N >> shift) > 8) shift++;
        hist_pack_kernel<<<NCHUNK, 1024, (size_t)NQ * 4, stream>>>(
            e32, flags, sd, hist, E, Et, chunk, NQ);
        chunk_scan_kernel<<<(NQ + 31) / 32, 256, 0, stream>>>(
            hist, base32, deg, NQ, N);
        ell_fill_kernel<<<NCHUNK * 8, 256, (size_t)(1 << shift), stream>>>(
            sd, base32, ell16, Et, chunk, NQ, shift);
    }

    // ---- layers ----
    const int gblocks = (N + 3) / 4;
    const int mblocks = (N + 63) / 64;
    const void* xin = d_in[0];

    // layer 0: 128 -> 32 (h-side). gather0 fuses layer-1 alpha (AFUSE).
    gemm_alpha_kernel<128, 32, __half><<<mblocks, 256, 0, stream>>>(
        xin, flags, 1, Wl[0], asr[0], adt[0], nullptr, bufH, as, ad,
        blkmax, 1, N, 0, 0, 0);
    max_finalize_kernel<<<1, 256, 0, stream>>>(blkmax, mblocks, maxbuf + 0);
    gat_gather_kernel<32, 0, 1, 1, 0><<<gblocks, 256, 0, stream>>>(
        deg, ell16, as, ad, maxbuf + 0, bufH, bl[0], bufX, N,
        wsd + 0, wsd + 128, as2, ad2, blkmax, nullptr, nullptr, nullptr);
    max_finalize_kernel<<<1, 256, 0, stream>>>(blkmax, gblocks, maxbuf + 2);

    // layer 1: 32 -> 64 (x-side), fused GEMM (GF=64) + layer-2 alpha.
    // reads x1 (bufX), writes x2 (bufH), as/ad = layer-2 logits.
    gat_gather_kernel<32, 1, 0, 0, 64><<<gblocks, 256, 0, stream>>>(
        deg, ell16, as2, ad2, maxbuf + 2, bufX, nullptr, bufH, N,
        wsd + 256, wsd + 384, as, ad, blkmax, Wl[1], bl[1], nullptr);
    max_finalize_kernel<<<1, 256, 0, stream>>>(blkmax, gblocks, maxbuf + 4);

    // layer 2: 64 -> 128 (x-side), fused GEMM (GF=128).
    // reads x2 (bufH), writes x3 (bufX).
    gat_gather_kernel<64, 1, 0, 0, 128><<<gblocks, 256, 0, stream>>>(
        deg, ell16, as, ad, maxbuf + 4, bufH, nullptr, bufX, N,
        nullptr, nullptr, nullptr, nullptr, nullptr, Wl[2], bl[2], nullptr);

    // layer 3: 128 -> 128 (h-side)
    gemm_alpha_kernel<128, 128, __half><<<mblocks, 256, 0, stream>>>(
        bufX, flags, 0, Wl[3], asr[3], adt[3], nullptr, bufH, as, ad,
        blkmax, 1, N, 1, 0, 0);
    max_finalize_kernel<<<1, 256, 0, stream>>>(blkmax, mblocks, maxbuf + 6);
    // gather3 fused with fc (GF=1): writes fp32 d_out directly.
    gat_gather_kernel<128, 0, 1, 0, 1><<<gblocks, 256, 0, stream>>>(
        deg, ell16, as, ad, maxbuf + 6, bufH, bl[3], nullptr, N,
        nullptr, nullptr, nullptr, nullptr, nullptr, fcW, fcb, (float*)d_out);
}

// Round 8
// 454.594 us; speedup vs baseline: 1.2502x; 1.2502x over previous
//
#include <hip/hip_runtime.h>
#include <hip/hip_bf16.h>
#include <hip/hip_fp16.h>

// ---------------------------------------------------------------------------
// GAT (4 layers + fc) on MI355X. ELL-gather formulation (no float atomics).
// flags[0]: float tensors bf16(1)/fp32(0); flags[1]: edges int64(1)/int32(0)
// fp32 compute; h AND inter-layer x stored fp16; fp32 output.
// R24: EXACT revert to R22 (best measured: 457.8us). R23's in-gather GEMM
//      fusion regressed 458->568: the 64-step __shfl broadcast is a SERIAL
//      chain of dependent ds_bpermute (~50cy each) feeding a serial FMA
//      accumulator -> ~4000 stall cycles appended to every gather wave
//      (116us/dispatch, VALU 31%, HBM 8%). Blocked GEMMs with LDS tiling do
//      that work fully pipelined; keep them as separate dispatches.
//      Evidence after R20/R21/R23: R22's configuration is the local optimum
//      for this decomposition; gather3 (50us, 155MB = 8 XCDs x 12.8MB
//      compulsory h-refetch @3.4TB/s random-read) is the roofline kernel.
// R22: AFUSE (layer-1 alpha in gather0 epilogue, 8-lane dot - cheap, kept),
//      relu_alpha (layer-2 alpha in gemm1), wvec merged into convert_params.
// R19: atomic-free global max (blkmax + 1-block finalize).
// R18: x-side aggregation for FIN<FOUT layers (1,2).
// R17: atomic-free ELL build (chunk-histogram counting sort).
// ---------------------------------------------------------------------------

__device__ __forceinline__ float bf2f(unsigned short w) {
    return __uint_as_float(((unsigned int)w) << 16);
}
__device__ __forceinline__ unsigned enc_f(float f) {
    unsigned u = __float_as_uint(f);
    return (u & 0x80000000u) ? ~u : (u | 0x80000000u);
}
__device__ __forceinline__ float dec_f(unsigned u) {
    unsigned v = (u & 0x80000000u) ? (u & 0x7FFFFFFFu) : ~u;
    return __uint_as_float(v);
}

#define ELL_K 96    // slots per dst: 192 B = exactly 3 cache lines
#define NCHUNK 256  // chunk-histogram chunks (= K_B grid; K_C assumes 8x32)

// --------------------------- dtype detection -------------------------------
__global__ void detect_kernel(const unsigned short* __restrict__ xw,
                              const int* __restrict__ ew,
                              int* __restrict__ flags,
                              unsigned* __restrict__ maxbuf)
{
    __shared__ int cnt_sane[256];
    __shared__ int cnt_nz[256];
    const int t = threadIdx.x;
    unsigned short w = xw[2 * t];
    int e = (w >> 7) & 0xff;
    cnt_sane[t] = (e >= 110 && e <= 133) ? 1 : 0;
    cnt_nz[t] = (ew[2 * t + 1] != 0) ? 1 : 0;
    if (t < 8) maxbuf[t] = 0u;
    __syncthreads();
    if (t == 0) {
        int s = 0, nz = 0;
        for (int i = 0; i < 256; ++i) { s += cnt_sane[i]; nz += cnt_nz[i]; }
        flags[0] = (s >= 128) ? 1 : 0;
        flags[1] = (nz == 0) ? 1 : 0;
    }
}

// ------------------- param conversion + fused wvec -------------------------
// blocks 0..17: convert tensor b. blocks 18,19: ws/wd for layers 1,2
// (ws = W @ a_src, wd = W @ a_dst), reading RAW inputs with inline cvt.
struct ParamPtrs {
    const void* src[18];
    int n[18];
    int off[18];
};

__global__ void convert_params_kernel(ParamPtrs pp, const int* __restrict__ flags,
                                      float* __restrict__ out, float* __restrict__ wsd)
{
    const int b = blockIdx.x;
    const int bf = flags[0];
    if (b < 18) {
        const int n = pp.n[b];
        const float* fp = (const float*)pp.src[b];
        const unsigned short* hp = (const unsigned short*)pp.src[b];
        float* o = out + pp.off[b];
        for (int i = threadIdx.x; i < n; i += blockDim.x)
            o[i] = bf ? bf2f(hp[i]) : fp[i];
        return;
    }
    const int l = b - 18;                     // 0: layer1 (32x64), 1: layer2 (64x128)
    const int wi = l ? 8 : 4;                 // param index of W
    const unsigned short* Wh  = (const unsigned short*)pp.src[wi];
    const float*          Wf  = (const float*)pp.src[wi];
    const unsigned short* Ash = (const unsigned short*)pp.src[wi + 1];
    const float*          Asf = (const float*)pp.src[wi + 1];
    const unsigned short* Adh = (const unsigned short*)pp.src[wi + 2];
    const float*          Adf = (const float*)pp.src[wi + 2];
    const int FIN  = l ? 64 : 32;
    const int FOUT = l ? 128 : 64;
    float* ws = wsd + l * 256;
    float* wd = ws + 128;
    const int k = threadIdx.x;
    if (k < FIN) {
        float s = 0.f, d = 0.f;
        for (int j = 0; j < FOUT; ++j) {
            const float w = bf ? bf2f(Wh[k * FOUT + j]) : Wf[k * FOUT + j];
            const float a = bf ? bf2f(Ash[j]) : Asf[j];
            const float c = bf ? bf2f(Adh[j]) : Adf[j];
            s += w * a;
            d += w * c;
        }
        ws[k] = s;
        wd[k] = d;
    }
}

// ---------------- global-max finalize (atomic-free) ------------------------
// Reduces nb float2 partial maxima -> maxSD[0..1] (enc_f format, plain store)
__global__ __launch_bounds__(256) void max_finalize_kernel(
    const float2* __restrict__ bm, int nb, unsigned* __restrict__ maxSD)
{
    __shared__ float sm[4][2];
    const int tx = threadIdx.x;
    float ms = -INFINITY, md = -INFINITY;
    for (int i = tx; i < nb; i += 256) {
        const float2 v = bm[i];
        ms = fmaxf(ms, v.x);
        md = fmaxf(md, v.y);
    }
    #pragma unroll
    for (int off = 32; off > 0; off >>= 1) {
        ms = fmaxf(ms, __shfl_down(ms, off, 64));
        md = fmaxf(md, __shfl_down(md, off, 64));
    }
    if ((tx & 63) == 0) { sm[tx >> 6][0] = ms; sm[tx >> 6][1] = md; }
    __syncthreads();
    if (tx == 0) {
        #pragma unroll
        for (int w = 1; w < 4; ++w) {
            ms = fmaxf(ms, sm[w][0]);
            md = fmaxf(md, sm[w][1]);
        }
        maxSD[0] = enc_f(ms);
        maxSD[1] = enc_f(md);
    }
}

// ---------------- K_B: per-chunk histogram + sd pack (LDS atomics only) ----
__global__ __launch_bounds__(1024) void hist_pack_kernel(
    const int* __restrict__ e, const int* __restrict__ flags,
    unsigned* __restrict__ sd, unsigned* __restrict__ hist,
    long long E, long long Et, int chunk, int NQ)
{
    extern __shared__ unsigned hcnt[];          // NQ words = ceil(N/4)*4 B
    const int c = blockIdx.x;
    for (int i = threadIdx.x; i < NQ; i += 1024) hcnt[i] = 0u;
    __syncthreads();
    const int f64 = flags[1];
    const long long c0 = (long long)c * chunk;
    long long c1 = c0 + chunk; if (c1 > Et) c1 = Et;
    for (long long t = c0 + threadIdx.x; t < c1; t += 1024) {
        int s, d;
        if (t >= E) { s = (int)(t - E); d = s; }
        else if (f64) { s = e[2 * t]; d = e[2 * E + 2 * t]; }
        else          { s = e[t];     d = e[E + t]; }
        sd[t] = (unsigned)s | ((unsigned)d << 16);
        atomicAdd(&hcnt[d >> 2], 1u << ((d & 3) << 3));
    }
    __syncthreads();
    unsigned* hrow = hist + (size_t)c * NQ;
    for (int i = threadIdx.x; i < NQ; i += 1024) hrow[i] = hcnt[i];
}

// ---------------- K_C: per-dst exclusive prefix over chunks ----------------
__global__ __launch_bounds__(256) void chunk_scan_kernel(
    const unsigned* __restrict__ hist, unsigned* __restrict__ base32,
    int* __restrict__ deg, int NQ, int N)
{
    __shared__ unsigned short sums[32][8][4];   // [dql][oct][byte]
    const int dql = threadIdx.x & 31;
    const int oct = threadIdx.x >> 5;           // 0..7, 32 chunks each
    const int dq  = blockIdx.x * 32 + dql;
    const int cbeg = oct * 32;

    unsigned s0 = 0, s1 = 0, s2 = 0, s3 = 0;
    if (dq < NQ) {
        const unsigned* hp = hist + (size_t)cbeg * NQ + dq;
        #pragma unroll 8
        for (int c = 0; c < 32; ++c) {
            const unsigned v = hp[(size_t)c * NQ];
            s0 += v & 0xffu;          s1 += (v >> 8) & 0xffu;
            s2 += (v >> 16) & 0xffu;  s3 += v >> 24;
        }
    }
    sums[dql][oct][0] = (unsigned short)s0;
    sums[dql][oct][1] = (unsigned short)s1;
    sums[dql][oct][2] = (unsigned short)s2;
    sums[dql][oct][3] = (unsigned short)s3;
    __syncthreads();

    unsigned r0 = 0, r1 = 0, r2 = 0, r3 = 0;    // exclusive octant prefix
    #pragma unroll
    for (int p = 0; p < 8; ++p) {
        if (p < oct) {
            r0 += sums[dql][p][0]; r1 += sums[dql][p][1];
            r2 += sums[dql][p][2]; r3 += sums[dql][p][3];
        }
    }
    if (dq >= NQ) return;

    if (oct == 7) {                              // totals -> deg
        const int d0 = dq * 4;
        const int t0 = (int)(r0 + s0), t1 = (int)(r1 + s1);
        const int t2 = (int)(r2 + s2), t3 = (int)(r3 + s3);
        if (d0 + 3 < N) {
            *(int4*)(deg + d0) = make_int4(t0, t1, t2, t3);
        } else {
            if (d0     < N) deg[d0]     = t0;
            if (d0 + 1 < N) deg[d0 + 1] = t1;
            if (d0 + 2 < N) deg[d0 + 2] = t2;
            if (d0 + 3 < N) deg[d0 + 3] = t3;
        }
    }

    // exclusive running bases for this octant's 32 chunks
    unsigned run0 = r0, run1 = r1, run2 = r2, run3 = r3;
    const unsigned* hp = hist + (size_t)cbeg * NQ + dq;
    unsigned* bp = base32 + (size_t)cbeg * NQ + dq;
    for (int c = 0; c < 32; ++c) {
        const unsigned v = hp[(size_t)c * NQ];
        const unsigned o = (run0 < 255u ? run0 : 255u)
                         | ((run1 < 255u ? run1 : 255u) << 8)
                         | ((run2 < 255u ? run2 : 255u) << 16)
                         | ((run3 < 255u ? run3 : 255u) << 24);
        bp[(size_t)c * NQ] = o;
        run0 += v & 0xffu;          run1 += (v >> 8) & 0xffu;
        run2 += (v >> 16) & 0xffu;  run3 += v >> 24;
    }
}

// ---------------- K_D: bucketed ELL fill (atomic-free globally) ------------
__global__ __launch_bounds__(256) void ell_fill_kernel(
    const unsigned* __restrict__ sd, const unsigned* __restrict__ base32,
    unsigned short* __restrict__ ell16, long long Et, int chunk, int NQ, int shift)
{
    extern __shared__ unsigned cnt[];            // (1<<shift)/4 words
    const int bucket = blockIdx.x & 7;
    const int c = blockIdx.x >> 3;
    const int words = (1 << shift) >> 2;
    for (int i = threadIdx.x; i < words; i += 256) cnt[i] = 0u;
    __syncthreads();
    const long long c0 = (long long)c * chunk;
    long long c1 = c0 + chunk; if (c1 > Et) c1 = Et;
    const unsigned* brow = base32 + (size_t)c * NQ;
    const int dlo = bucket << shift;
    for (long long i = c0 + threadIdx.x; i < c1; i += 256) {
        const unsigned v = sd[i];
        const int d = (int)(v >> 16);
        if ((d >> shift) != bucket) continue;
        const int dl = d - dlo;
        const unsigned sh = (unsigned)((dl & 3) << 3);
        const unsigned old = atomicAdd(&cnt[dl >> 2], 1u << sh);
        const unsigned lr = (old >> sh) & 0xffu;
        const unsigned b = (brow[d >> 2] >> ((d & 3) << 3)) & 0xffu;
        const unsigned slot = b + lr;
        if (slot < ELL_K)
            ell16[(long long)d * ELL_K + slot] = (unsigned short)(v & 0xffffu);
    }
}

// ------------------------------- GEMM --------------------------------------
// Register-blocked: 256 threads, TM=64 rows/block; thread (cg,rt) = RR rows x
// 4 cols. W [FIN][FOUT] lane-coalesced. Fused alpha dots (fp32 acc) + per-
// block max -> blkmax (no atomics). relu_alpha: alpha from relu(acc) (x-side
// layers where acc IS the next layer's input x). Input: external (bf16/fp32,
// x_ext=1) or fp16 ws buffer. Output OT: fp16 (layers) or fp32 (fc/d_out).
struct Half4 { __half2 a, b; };

__device__ __forceinline__ void store4(float* h, long long idx, const float* a) {
    *(float4*)(h + idx) = make_float4(a[0], a[1], a[2], a[3]);
}
__device__ __forceinline__ void store4(__half* h, long long idx, const float* a) {
    Half4 v;
    v.a = __floats2half2_rn(a[0], a[1]);
    v.b = __floats2half2_rn(a[2], a[3]);
    *(Half4*)(h + idx) = v;
}

template <int FIN, int FOUT, typename OT>
__global__ __launch_bounds__(256) void gemm_alpha_kernel(
    const void* __restrict__ xv, const int* __restrict__ flags, int x_ext,
    const float* __restrict__ W, const float* __restrict__ a_src,
    const float* __restrict__ a_dst, const float* __restrict__ bias,
    OT* __restrict__ h,
    float* __restrict__ alpha_s, float* __restrict__ alpha_d,
    float2* __restrict__ blkmax, int has_alpha,
    int N, int relu_in, int has_bias, int relu_alpha)
{
    constexpr int CG = FOUT / 4;
    constexpr int RT = 256 / CG;
    constexpr int RR = 64 / RT;
    constexpr int TM = 64;
    constexpr int XP = FIN + 4;
    constexpr int Q  = FIN / 8;      // 8-float groups per row

    __shared__ float xs[TM * XP];
    __shared__ float red[2][TM][CG + 1];

    const int tx = threadIdx.x;
    const int cg = tx & (CG - 1);
    const int rt = tx / CG;
    const long long base = (long long)blockIdx.x * TM;

    const int xbf = x_ext ? flags[0] : 0;

    for (int idx = tx; idx < TM * Q; idx += 256) {
        const int r  = idx / Q;
        const int c8 = idx - r * Q;
        const long long grow = base + r;
        float v[8] = {0.f, 0.f, 0.f, 0.f, 0.f, 0.f, 0.f, 0.f};
        if (grow < N) {
            const long long gi = grow * FIN + 8 * c8;
            if (x_ext) {
                if (xbf) {
                    const unsigned short* xp = (const unsigned short*)xv + gi;
                    #pragma unroll
                    for (int u = 0; u < 8; ++u) v[u] = bf2f(xp[u]);
                } else {
                    const float4 f0 = *((const float4*)((const float*)xv + gi));
                    const float4 f1 = *((const float4*)((const float*)xv + gi + 4));
                    v[0] = f0.x; v[1] = f0.y; v[2] = f0.z; v[3] = f0.w;
                    v[4] = f1.x; v[5] = f1.y; v[6] = f1.z; v[7] = f1.w;
                }
            } else {
                const float4 raw = *((const float4*)((const __half*)xv + gi)); // 8 halfs
                const __half2* q = (const __half2*)&raw;
                const float2 a0 = __half22float2(q[0]);
                const float2 a1 = __half22float2(q[1]);
                const float2 a2 = __half22float2(q[2]);
                const float2 a3 = __half22float2(q[3]);
                v[0] = a0.x; v[1] = a0.y; v[2] = a1.x; v[3] = a1.y;
                v[4] = a2.x; v[5] = a2.y; v[6] = a3.x; v[7] = a3.y;
            }
            if (relu_in) {
                #pragma unroll
                for (int u = 0; u < 8; ++u) v[u] = fmaxf(v[u], 0.f);
            }
        }
        *(float4*)&xs[r * XP + 8 * c8]     = make_float4(v[0], v[1], v[2], v[3]);
        *(float4*)&xs[r * XP + 8 * c8 + 4] = make_float4(v[4], v[5], v[6], v[7]);
    }
    __syncthreads();

    float acc[RR][4];
    #pragma unroll
    for (int rr = 0; rr < RR; ++rr)
        { acc[rr][0] = acc[rr][1] = acc[rr][2] = acc[rr][3] = 0.f; }

    const int r0 = rt * RR;
    #pragma unroll 4
    for (int k = 0; k < FIN; ++k) {
        const float4 w4 = *(const float4*)(W + k * FOUT + 4 * cg);
        #pragma unroll
        for (int rr = 0; rr < RR; ++rr) {
            const float xval = xs[(r0 + rr) * XP + k];
            acc[rr][0] += xval * w4.x;
            acc[rr][1] += xval * w4.y;
            acc[rr][2] += xval * w4.z;
            acc[rr][3] += xval * w4.w;
        }
    }

    if (has_bias) {
        const float4 b4 = *(const float4*)(bias + 4 * cg);
        #pragma unroll
        for (int rr = 0; rr < RR; ++rr) {
            acc[rr][0] += b4.x; acc[rr][1] += b4.y;
            acc[rr][2] += b4.z; acc[rr][3] += b4.w;
        }
    }

    #pragma unroll
    for (int rr = 0; rr < RR; ++rr) {
        const long long grow = base + r0 + rr;
        if (grow < N)
            store4(h, grow * FOUT + 4 * cg, acc[rr]);
    }

    if (has_alpha) {
        const float4 as4 = *(const float4*)(a_src + 4 * cg);
        const float4 ad4 = *(const float4*)(a_dst + 4 * cg);
        #pragma unroll
        for (int rr = 0; rr < RR; ++rr) {
            float b0 = acc[rr][0], b1 = acc[rr][1], b2 = acc[rr][2], b3 = acc[rr][3];
            if (relu_alpha) {
                b0 = fmaxf(b0, 0.f); b1 = fmaxf(b1, 0.f);
                b2 = fmaxf(b2, 0.f); b3 = fmaxf(b3, 0.f);
            }
            red[0][r0 + rr][cg] = b0 * as4.x + b1 * as4.y + b2 * as4.z + b3 * as4.w;
            red[1][r0 + rr][cg] = b0 * ad4.x + b1 * ad4.y + b2 * ad4.z + b3 * ad4.w;
        }
        __syncthreads();
        if (tx < TM) {            // TM == 64: exactly wave 0
            float ss = 0.f, sd = 0.f;
            #pragma unroll
            for (int j = 0; j < CG; ++j) {
                ss += red[0][tx][j];
                sd += red[1][tx][j];
            }
            const long long grow = base + tx;
            const bool valid = grow < N;
            if (valid) { alpha_s[grow] = ss; alpha_d[grow] = sd; }
            float ms = valid ? ss : -INFINITY;
            float md = valid ? sd : -INFINITY;
            #pragma unroll
            for (int off = 32; off > 0; off >>= 1) {
                ms = fmaxf(ms, __shfl_down(ms, off, 64));
                md = fmaxf(md, __shfl_down(md, off, 64));
            }
            if (tx == 0)
                blkmax[blockIdx.x] = make_float2(ms, md);
        }
    }
}

// --------------------------- gather (per-dst wave) -------------------------
// Single pass: p = exp(leaky(as[s]+ad[d]) - M), M = global max shift.
// ELL: dst d's edges at ell16[d*96 .. d*96+cnt). h fp16; output fp16.
// XRELU: apply relu to gathered rows (x-side aggregation for FIN<FOUT layers)
// ADDB:  add bias in epilogue (h-side aggregation: final layer output)
// AFUSE: fused next-layer alpha: asO/adO = relu(out)·wsA/wdA + per-block max
//        (layer-0 gather computes layer-1 logits from x1 live in registers).
// Inner loop: R19 structure EXACTLY (4-wide unpredicated burst; dead slots
// shfl p=0 -> FMAs add 0; loads hit row 0, L1-hot). MLP+occupancy optimum.
template <int F, int XRELU, int ADDB, int AFUSE>
__global__ __launch_bounds__(256) void gat_gather_kernel(
    const int* __restrict__ deg, const unsigned short* __restrict__ ell16,
    const float* __restrict__ as, const float* __restrict__ ad,
    const unsigned* __restrict__ maxSD,
    const __half* __restrict__ h, const float* __restrict__ bias,
    __half* __restrict__ out, int N,
    const float* __restrict__ wsA, const float* __restrict__ wdA,
    float* __restrict__ asO, float* __restrict__ adO,
    float2* __restrict__ bmax)
{
    constexpr int LPE = F / 8;       // lanes per edge (4,8,16)
    constexpr int EPJ = 64 / LPE;    // edges per u-step (16,8,4)

    const int wslot = threadIdx.x >> 6;
    const int lane = threadIdx.x & 63;
    const int d = blockIdx.x * 4 + wslot;
    const bool dvalid = d < N;
    if (!AFUSE && !dvalid) return;

    float ssA = -INFINITY, sdA = -INFINITY;   // per-wave alpha (lane 0 after reduce)

    if (dvalid) {
        const float M = dec_f(maxSD[0]) + dec_f(maxSD[1]);
        const int cnt_all = min(deg[d], ELL_K);
        const long long e0 = (long long)d * ELL_K;
        const float add = ad[d];

        const int sub = lane / LPE;          // edge sub-slot
        const int fl  = (lane % LPE) * 8;    // feature offset (8 feats/lane)

        float den = 0.f;
        float a0 = 0.f, a1 = 0.f, a2 = 0.f, a3 = 0.f;
        float a4 = 0.f, a5 = 0.f, a6 = 0.f, a7 = 0.f;
        for (int base = 0; base < cnt_all; base += 64) {
            const int e = base + lane;
            float p = 0.f;
            int s = 0;
            if (e < cnt_all) {
                s = (int)ell16[e0 + e];
                float v = as[s] + add;
                v = (v > 0.f) ? v : 0.2f * v;
                p = expf(v - M);
            }
            den += p;
            const int cnt = min(64, cnt_all - base);
            // 4-wide burst: 4 independent float4 (=8 fp16) loads, then accumulate
            for (int j = 0; j < cnt; j += 4 * EPJ) {
                float pj[4];
                float4 hv[4];
                #pragma unroll
                for (int u = 0; u < 4; ++u) {
                    const int jj = j + u * EPJ + sub;       // < 64 always
                    pj[u] = __shfl(p, jj, 64);              // 0 for OOB slots
                    const int sj = __shfl(s, jj, 64);
                    hv[u] = *(const float4*)(h + (long long)sj * F + fl);
                }
                #pragma unroll
                for (int u = 0; u < 4; ++u) {
                    const __half2* q = (const __half2*)&hv[u];
                    float2 f0 = __half22float2(q[0]);
                    float2 f1 = __half22float2(q[1]);
                    float2 f2 = __half22float2(q[2]);
                    float2 f3 = __half22float2(q[3]);
                    if (XRELU) {
                        f0.x = fmaxf(f0.x, 0.f); f0.y = fmaxf(f0.y, 0.f);
                        f1.x = fmaxf(f1.x, 0.f); f1.y = fmaxf(f1.y, 0.f);
                        f2.x = fmaxf(f2.x, 0.f); f2.y = fmaxf(f2.y, 0.f);
                        f3.x = fmaxf(f3.x, 0.f); f3.y = fmaxf(f3.y, 0.f);
                    }
                    a0 += pj[u] * f0.x;  a1 += pj[u] * f0.y;
                    a2 += pj[u] * f1.x;  a3 += pj[u] * f1.y;
                    a4 += pj[u] * f2.x;  a5 += pj[u] * f2.y;
                    a6 += pj[u] * f3.x;  a7 += pj[u] * f3.y;
                }
            }
        }
        #pragma unroll
        for (int off = 32; off > 0; off >>= 1)
            den += __shfl_down(den, off, 64);
        den = __shfl(den, 0, 64);
        const float inv = 1.f / den;

        // combine edge sub-slots (lanes LPE apart hold same feature)
        #pragma unroll
        for (int off = 32; off >= LPE; off >>= 1) {
            a0 += __shfl_down(a0, off, 64);
            a1 += __shfl_down(a1, off, 64);
            a2 += __shfl_down(a2, off, 64);
            a3 += __shfl_down(a3, off, 64);
            a4 += __shfl_down(a4, off, 64);
            a5 += __shfl_down(a5, off, 64);
            a6 += __shfl_down(a6, off, 64);
            a7 += __shfl_down(a7, off, 64);
        }
        if (lane < LPE) {
            float v0, v1, v2, v3, v4, v5, v6, v7;
            if (ADDB) {
                const float4 bA = *(const float4*)(bias + fl);
                const float4 bB = *(const float4*)(bias + fl + 4);
                v0 = bA.x + a0 * inv;  v1 = bA.y + a1 * inv;
                v2 = bA.z + a2 * inv;  v3 = bA.w + a3 * inv;
                v4 = bB.x + a4 * inv;  v5 = bB.y + a5 * inv;
                v6 = bB.z + a6 * inv;  v7 = bB.w + a7 * inv;
            } else {
                v0 = a0 * inv;  v1 = a1 * inv;  v2 = a2 * inv;  v3 = a3 * inv;
                v4 = a4 * inv;  v5 = a5 * inv;  v6 = a6 * inv;  v7 = a7 * inv;
            }
            float4 pack;
            __half2* q = (__half2*)&pack;
            q[0] = __floats2half2_rn(v0, v1);
            q[1] = __floats2half2_rn(v2, v3);
            q[2] = __floats2half2_rn(v4, v5);
            q[3] = __floats2half2_rn(v6, v7);
            *(float4*)(out + (long long)d * F + fl) = pack;   // 8 halfs

            if (AFUSE) {
                // next-layer alpha: relu(out) . wsA / wdA  (fp32, pre-rounding)
                const float4 wA = *(const float4*)(wsA + fl);
                const float4 wB = *(const float4*)(wsA + fl + 4);
                const float4 dA = *(const float4*)(wdA + fl);
                const float4 dB = *(const float4*)(wdA + fl + 4);
                const float r0 = fmaxf(v0, 0.f), r1 = fmaxf(v1, 0.f);
                const float r2 = fmaxf(v2, 0.f), r3 = fmaxf(v3, 0.f);
                const float r4 = fmaxf(v4, 0.f), r5 = fmaxf(v5, 0.f);
                const float r6 = fmaxf(v6, 0.f), r7 = fmaxf(v7, 0.f);
                float ss = r0 * wA.x + r1 * wA.y + r2 * wA.z + r3 * wA.w
                         + r4 * wB.x + r5 * wB.y + r6 * wB.z + r7 * wB.w;
                float sd = r0 * dA.x + r1 * dA.y + r2 * dA.z + r3 * dA.w
                         + r4 * dB.x + r5 * dB.y + r6 * dB.z + r7 * dB.w;
                #pragma unroll
                for (int off = LPE / 2; off > 0; off >>= 1) {
                    ss += __shfl_down(ss, off, 64);
                    sd += __shfl_down(sd, off, 64);
                }
                if (lane == 0) {
                    asO[d] = ss;
                    adO[d] = sd;
                    ssA = ss;
                    sdA = sd;
                }
            }
        }
    }

    if (AFUSE) {
        __shared__ float smx[4][2];
        if (lane == 0) {
            smx[wslot][0] = dvalid ? ssA : -INFINITY;
            smx[wslot][1] = dvalid ? sdA : -INFINITY;
        }
        __syncthreads();
        if (threadIdx.x == 0) {
            float ms = smx[0][0], md = smx[0][1];
            #pragma unroll
            for (int w = 1; w < 4; ++w) {
                ms = fmaxf(ms, smx[w][0]);
                md = fmaxf(md, smx[w][1]);
            }
            bmax[blockIdx.x] = make_float2(ms, md);
        }
    }
}

// ------------------------------- launch ------------------------------------
extern "C" void kernel_launch(void* const* d_in, const int* in_sizes, int n_in,
                              void* d_out, int out_size, void* d_ws, size_t ws_size,
                              hipStream_t stream)
{
    const int INP = 128;
    const int N = in_sizes[0] / INP;                 // 50000 (< 65536: ushort ok)
    const long long E = in_sizes[1] / 2;             // 1600000
    const long long Et = E + N;

    const int Fin[4]  = {128, 32, 64, 128};
    const int Fout[4] = {32, 64, 128, 128};

    const int NQ = (N + 3) / 4;                      // hist/base words per chunk
    const size_t histBytes = (size_t)NQ * 4 * NCHUNK;
    const size_t xbufBytes = (size_t)N * 128 * sizeof(__half);
    const size_t bigBytes  = histBytes > xbufBytes ? histBytes : xbufBytes;

    // ---- workspace layout (~44 MB) ----
    char* p = (char*)d_ws;
    auto alloc = [&](size_t bytes) {
        char* r = p;
        p += (bytes + 255) & ~(size_t)255;
        return r;
    };
    __half*   bufH    = (__half*)  alloc(bigBytes);  // aliases hist (K_B..K_C)
    __half*   bufX    = (__half*)  alloc(bigBytes);  // aliases base (K_C..K_D)
    float*    as      = (float*)   alloc((size_t)N * sizeof(float));
    float*    ad      = (float*)   alloc((size_t)N * sizeof(float));
    float*    as2     = (float*)   alloc((size_t)N * sizeof(float));
    float*    ad2     = (float*)   alloc((size_t)N * sizeof(float));
    int*      deg     = (int*)     alloc((size_t)N * sizeof(int));
    unsigned short* ell16 = (unsigned short*)alloc((size_t)N * ELL_K * sizeof(unsigned short));
    unsigned* sd      = (unsigned*)alloc((size_t)Et * sizeof(unsigned));
    unsigned* maxbuf  = (unsigned*)alloc(64);
    int*      flags   = (int*)     alloc(64);
    float*    wsd     = (float*)   alloc(512 * sizeof(float));
    float2*   blkmax  = (float2*)  alloc(16384 * sizeof(float2));
    float*    params  = (float*)   alloc(64 * 1024 * sizeof(float));
    (void)ws_size;

    unsigned* hist   = (unsigned*)bufH;   // dead before gemm0 writes bufH
    unsigned* base32 = (unsigned*)bufX;   // dead before gather0 writes bufX

    // ---- dtype detection + maxbuf init ----
    detect_kernel<<<1, 256, 0, stream>>>((const unsigned short*)d_in[0],
                                         (const int*)d_in[1], flags, maxbuf);

    // ---- param conversion + wvec (blocks 18,19) ----
    ParamPtrs pp;
    int off = 0;
    {
        int k = 0;
        for (int i = 0; i < 4; ++i) {
            pp.n[k++] = Fin[i] * Fout[i];
            pp.n[k++] = Fout[i];
            pp.n[k++] = Fout[i];
            pp.n[k++] = Fout[i];
        }
        pp.n[16] = 128 * 16;
        pp.n[17] = 16;
        for (int i = 0; i < 18; ++i) {
            pp.src[i] = d_in[2 + i];
            pp.off[i] = off;
            off += pp.n[i];
        }
    }
    convert_params_kernel<<<20, 256, 0, stream>>>(pp, flags, params, wsd);

    const float* Wl[4], *asr[4], *adt[4], *bl[4];
    for (int i = 0; i < 4; ++i) {
        Wl[i]  = params + pp.off[4 * i + 0];
        asr[i] = params + pp.off[4 * i + 1];
        adt[i] = params + pp.off[4 * i + 2];
        bl[i]  = params + pp.off[4 * i + 3];
    }
    const float* fcW = params + pp.off[16];
    const float* fcb = params + pp.off[17];

    const int* e32 = (const int*)d_in[1];

    // ---- ELL build: chunk histogram -> scan -> bucketed fill (atomic-free) -
    {
        const int chunk = (int)((Et + NCHUNK - 1) / NCHUNK);
        int shift = 0;
        while ((N >> shift) > 8) shift++;
        hist_pack_kernel<<<NCHUNK, 1024, (size_t)NQ * 4, stream>>>(
            e32, flags, sd, hist, E, Et, chunk, NQ);
        chunk_scan_kernel<<<(NQ + 31) / 32, 256, 0, stream>>>(
            hist, base32, deg, NQ, N);
        ell_fill_kernel<<<NCHUNK * 8, 256, (size_t)(1 << shift), stream>>>(
            sd, base32, ell16, Et, chunk, NQ, shift);
    }

    // ---- layers ----
    const int gblocks = (N + 3) / 4;
    const int mblocks = (N + 63) / 64;
    const void* xin = d_in[0];

    // layer 0: 128 -> 32 (h-side). gather0 fuses layer-1 alpha (AFUSE).
    gemm_alpha_kernel<128, 32, __half><<<mblocks, 256, 0, stream>>>(
        xin, flags, 1, Wl[0], asr[0], adt[0], nullptr, bufH, as, ad,
        blkmax, 1, N, 0, 0, 0);
    max_finalize_kernel<<<1, 256, 0, stream>>>(blkmax, mblocks, maxbuf + 0);
    gat_gather_kernel<32, 0, 1, 1><<<gblocks, 256, 0, stream>>>(
        deg, ell16, as, ad, maxbuf + 0, bufH, bl[0], bufX, N,
        wsd + 0, wsd + 128, as2, ad2, blkmax);
    max_finalize_kernel<<<1, 256, 0, stream>>>(blkmax, gblocks, maxbuf + 2);

    // layer 1: 32 -> 64 (x-side). gemm1 fuses layer-2 alpha (relu_alpha).
    gat_gather_kernel<32, 1, 0, 0><<<gblocks, 256, 0, stream>>>(
        deg, ell16, as2, ad2, maxbuf + 2, bufX, nullptr, bufH, N,
        nullptr, nullptr, nullptr, nullptr, nullptr);                 // y1 -> bufH
    gemm_alpha_kernel<32, 64, __half><<<mblocks, 256, 0, stream>>>(
        bufH, flags, 0, Wl[1], wsd + 256, wsd + 384, bl[1], bufX, as, ad,
        blkmax, 1, N, 0, 1, 1);
    max_finalize_kernel<<<1, 256, 0, stream>>>(blkmax, mblocks, maxbuf + 4);

    // layer 2: 64 -> 128 (x-side)
    gat_gather_kernel<64, 1, 0, 0><<<gblocks, 256, 0, stream>>>(
        deg, ell16, as, ad, maxbuf + 4, bufX, nullptr, bufH, N,
        nullptr, nullptr, nullptr, nullptr, nullptr);                 // y2 -> bufH
    gemm_alpha_kernel<64, 128, __half><<<mblocks, 256, 0, stream>>>(
        bufH, flags, 0, Wl[2], nullptr, nullptr, bl[2], bufX, nullptr, nullptr,
        nullptr, 0, N, 0, 1, 0);

    // layer 3: 128 -> 128 (h-side)
    gemm_alpha_kernel<128, 128, __half><<<mblocks, 256, 0, stream>>>(
        bufX, flags, 0, Wl[3], asr[3], adt[3], nullptr, bufH, as, ad,
        blkmax, 1, N, 1, 0, 0);
    max_finalize_kernel<<<1, 256, 0, stream>>>(blkmax, mblocks, maxbuf + 6);
    gat_gather_kernel<128, 0, 1, 0><<<gblocks, 256, 0, stream>>>(
        deg, ell16, as, ad, maxbuf + 6, bufH, bl[3], bufX, N,
        nullptr, nullptr, nullptr, nullptr, nullptr);

    // final fc: out = relu(x) @ fc_W + fc_b (fp32 out)
    gemm_alpha_kernel<128, 16, float><<<mblocks, 256, 0, stream>>>(
        bufX, flags, 0, fcW, nullptr, nullptr, fcb,
        (float*)d_out, nullptr, nullptr, nullptr, 0, N, 1, 1, 0);
}